// Round 3
// baseline (3222.415 us; speedup 1.0000x reference)
//
#include <hip/hip_runtime.h>

// Grid constants (padded 66^3)
#define GD   66
#define GHW  (66*66)
#define GDHW (66*66*66)
#define CI   32
#define CO   32
#define NBINS (2*64*64*64)      // batch * 64^3 = 524288 bins
#define NSCAN_BLOCKS 2048       // NBINS / 256

__device__ __forceinline__ void atomAdd(float* p, float v) {
    unsafeAtomicAdd(p, v);      // native global_atomic_add_f32 on gfx950
}

// ---------------- sort-gather path ----------------
// Rationale (rocprof r0/r1): scatter issues 345.6M global atomics; measured
// 129 ops/cycle == 128 L2 channels * 1 atomic/cycle -> hard op-rate wall at
// ~1117us regardless of kernel structure. Gather eliminates the atomics.

// K1: histogram + per-particle (bin, rank)
__global__ __launch_bounds__(256) void hist_kernel(
    const float* __restrict__ pos, unsigned* __restrict__ counts,
    unsigned* __restrict__ binA, unsigned* __restrict__ rankA,
    int N, int total)
{
    int gp = blockIdx.x*256 + threadIdx.x;
    if (gp >= total) return;
    float px = pos[gp*3+0]*64.f, py = pos[gp*3+1]*64.f, pz = pos[gp*3+2]*64.f;
    int bx = (int)px, by = (int)py, bz = (int)pz;     // base in [0,63]
    int b  = (gp >= N) ? 1 : 0;
    unsigned bin = (((unsigned)(b*64 + bx))*64u + (unsigned)by)*64u + (unsigned)bz;
    unsigned r = atomicAdd(&counts[bin], 1u);
    binA[gp] = bin; rankA[gp] = r;
}

// S1: per-block (256 bins) local exclusive scan + block sums
__global__ __launch_bounds__(256) void scan1_kernel(
    const unsigned* __restrict__ counts, unsigned* __restrict__ offs,
    unsigned* __restrict__ bsum)
{
    __shared__ unsigned ws[4];
    int i = blockIdx.x*256 + threadIdx.x;
    int lane = threadIdx.x & 63, wid = threadIdx.x >> 6;
    unsigned v = counts[i], s = v;
    #pragma unroll
    for (int d = 1; d < 64; d <<= 1) { unsigned n = __shfl_up(s, d, 64); if (lane >= d) s += n; }
    if (lane == 63) ws[wid] = s;
    __syncthreads();
    if (threadIdx.x == 0) {
        unsigned r = 0;
        for (int w = 0; w < 4; ++w) { unsigned t = ws[w]; ws[w] = r; r += t; }
        bsum[blockIdx.x] = r;
    }
    __syncthreads();
    offs[i] = ws[wid] + s - v;
}

// S2: single block scans the 2048 block sums (exclusive, in place)
__global__ __launch_bounds__(256) void scan2_kernel(unsigned* __restrict__ bsum)
{
    __shared__ unsigned ws[4];
    __shared__ unsigned runsh;
    if (threadIdx.x == 0) runsh = 0;
    __syncthreads();
    int lane = threadIdx.x & 63, wid = threadIdx.x >> 6;
    for (int c = 0; c < NSCAN_BLOCKS; c += 256) {
        unsigned v = bsum[c + threadIdx.x], s = v;
        #pragma unroll
        for (int d = 1; d < 64; d <<= 1) { unsigned n = __shfl_up(s, d, 64); if (lane >= d) s += n; }
        if (lane == 63) ws[wid] = s;
        __syncthreads();
        unsigned run = runsh;
        __syncthreads();                    // all reads of runsh/ws done
        if (threadIdx.x == 0) {
            unsigned r = 0;
            for (int w = 0; w < 4; ++w) { unsigned t = ws[w]; ws[w] = r; r += t; }
            runsh = run + r;
        }
        __syncthreads();                    // ws prefixes + runsh ready
        bsum[c + threadIdx.x] = run + ws[wid] + s - v;
        __syncthreads();                    // protect ws for next chunk
    }
}

// S3: add block prefix; set offs[NBINS] = total
__global__ __launch_bounds__(256) void scan3_kernel(
    unsigned* __restrict__ offs, const unsigned* __restrict__ bsum, int total)
{
    int i = blockIdx.x*256 + threadIdx.x;
    offs[i] += bsum[blockIdx.x];
    if (i == 0) offs[NBINS] = (unsigned)total;
}

// K3: reorder particles into bin-sorted SoA: X[p][32], W[p][9] (spline weights)
__global__ __launch_bounds__(256) void reorder_kernel(
    const float* __restrict__ x, const float* __restrict__ pos,
    const unsigned* __restrict__ offs, const unsigned* __restrict__ binA,
    const unsigned* __restrict__ rankA,
    float* __restrict__ X, float* __restrict__ W, int total)
{
    int gp = blockIdx.x*256 + threadIdx.x;
    if (gp >= total) return;
    unsigned dst = offs[binA[gp]] + rankA[gp];
    const float4* xs = (const float4*)(x + (size_t)gp*32);
    float4* xd = (float4*)(X + (size_t)dst*32);
    #pragma unroll
    for (int i = 0; i < 8; ++i) xd[i] = xs[i];
    float px = pos[gp*3+0]*64.f, py = pos[gp*3+1]*64.f, pz = pos[gp*3+2]*64.f;
    int bx = (int)px, by = (int)py, bz = (int)pz;
    float fx = px-bx-0.5f, fy = py-by-0.5f, fz = pz-bz-0.5f;
    float* w = W + (size_t)dst*9;
    w[0]=0.5f*(0.5f-fx)*(0.5f-fx); w[1]=0.75f-fx*fx; w[2]=0.5f*(0.5f+fx)*(0.5f+fx);
    w[3]=0.5f*(0.5f-fy)*(0.5f-fy); w[4]=0.75f-fy*fy; w[5]=0.5f*(0.5f+fy)*(0.5f+fy);
    w[6]=0.5f*(0.5f-fz)*(0.5f-fz); w[7]=0.75f-fz*fz; w[8]=0.5f*(0.5f+fz)*(0.5f+fz);
}

// K4: gather. One block per (b, cx, cy) z-column; half-wave (lane=co) per cell.
// Offset-pair loop t=(oi,oj) OUTER with kreg[3][32] register-resident (static
// ok indexing -> no scratch); particles inner; zero atomics; output written
// directly in [b][co][cell] layout via small LDS transpose.
__global__ __launch_bounds__(256) void gather_kernel(
    const float* __restrict__ X, const float* __restrict__ W,
    const unsigned* __restrict__ offs, const float* __restrict__ kern,
    const float* __restrict__ bias, float* __restrict__ out)
{
    __shared__ float tile[GD][33];
    const int bid = blockIdx.x;                 // 0 .. 2*66*66-1
    const int b   = bid / (66*66);
    const int rr  = bid % (66*66);
    const int cx  = rr / 66, cy = rr % 66;
    const int co   = threadIdx.x & 31;
    const int half = threadIdx.x >> 5;          // 0..7
    const float bco = bias[co];

    float acc[9];
    #pragma unroll
    for (int k = 0; k < 9; ++k) acc[k] = 0.f;

    for (int t = 0; t < 9; ++t) {               // t = oi*3 + oj
        const int oi = t / 3, oj = t % 3;
        const int gx = cx - oi, gy = cy - oj;
        if ((unsigned)gx > 63u || (unsigned)gy > 63u) continue;   // block-uniform

        float kreg[3][32];                       // K[oi][oj][ok][ci][co]
        #pragma unroll
        for (int ok = 0; ok < 3; ++ok) {
            const float* kp = kern + (size_t)(t*3 + ok)*1024 + co;
            #pragma unroll
            for (int ci = 0; ci < 32; ++ci) kreg[ok][ci] = kp[ci*32];
        }
        const unsigned binbase = (((unsigned)(b*64 + gx))*64u + (unsigned)gy)*64u;

        #pragma unroll
        for (int k = 0; k < 9; ++k) {
            const int cz = half + 8*k;
            if (cz < GD) {
                #pragma unroll
                for (int ok = 0; ok < 3; ++ok) {
                    const int gz = cz - ok;
                    if ((unsigned)gz > 63u) continue;   // half-uniform
                    const unsigned bin = binbase + (unsigned)gz;
                    const unsigned s = offs[bin], e = offs[bin+1];
                    for (unsigned p = s; p < e; ++p) {
                        const float4* xp = (const float4*)(X + (size_t)p*32);
                        float xx[32];
                        #pragma unroll
                        for (int i = 0; i < 8; ++i) {
                            float4 v = xp[i];
                            xx[4*i+0]=v.x; xx[4*i+1]=v.y; xx[4*i+2]=v.z; xx[4*i+3]=v.w;
                        }
                        const float* wp = W + (size_t)p*9;
                        float w = wp[oi]*wp[3+oj]*wp[6+ok];
                        float dot = 0.f;
                        #pragma unroll
                        for (int ci = 0; ci < 32; ++ci) dot += xx[ci]*kreg[ok][ci];
                        acc[k] += w*(dot + bco);
                    }
                }
            }
        }
    }

    #pragma unroll
    for (int k = 0; k < 9; ++k) {
        const int cz = half + 8*k;
        if (cz < GD) tile[cz][co] = acc[k];
    }
    __syncthreads();
    const size_t obase = (size_t)b*32*GDHW + (size_t)(cx*GHW + cy*GD);
    for (int idx = threadIdx.x; idx < 32*GD; idx += 256) {
        const int c2 = idx / GD, z2 = idx % GD;  // consecutive lanes -> consecutive z2
        out[obase + (size_t)c2*GDHW + z2] = tile[z2][c2];
    }
}

// ---------------- fallback: direct atomic scatter (r0 baseline, CELLCO=false) ----------------
__global__ __launch_bounds__(256) void p2g_fallback(
    const float* __restrict__ x, const float* __restrict__ pos,
    const float* __restrict__ kern, const float* __restrict__ bias,
    float* __restrict__ dst, int N, int nPairs)
{
    const int co   = threadIdx.x & 31;
    const int half = threadIdx.x >> 5;
    const float bco = bias[co];
    const int halvesTotal = gridDim.x * 8;

    for (int t = 0; t < 9; ++t) {
        const int oi = t / 3, oj = t - 3*oi;
        float kreg[3][32];
        #pragma unroll
        for (int ok = 0; ok < 3; ++ok) {
            const float* kp = kern + (size_t)(t*3 + ok)*1024 + co;
            #pragma unroll
            for (int ci = 0; ci < 32; ++ci) kreg[ok][ci] = kp[ci*32];
        }
        for (int pp = blockIdx.x*8 + half; pp < nPairs; pp += halvesTotal) {
            const int g0 = pp*2;
            float xr[2][32];
            #pragma unroll
            for (int p = 0; p < 2; ++p) {
                const float4* xp = (const float4*)(x + (size_t)(g0+p)*CI);
                #pragma unroll
                for (int i = 0; i < 8; ++i) {
                    float4 v = xp[i];
                    xr[p][4*i+0]=v.x; xr[p][4*i+1]=v.y; xr[p][4*i+2]=v.z; xr[p][4*i+3]=v.w;
                }
            }
            float wxy[2], wz[2][3]; int cb[2], bsel[2];
            #pragma unroll
            for (int p = 0; p < 2; ++p) {
                const int gp = g0 + p;
                float px = pos[gp*3+0]*64.f, py = pos[gp*3+1]*64.f, pz = pos[gp*3+2]*64.f;
                int bx = (int)px, by = (int)py, bz = (int)pz;
                float fx = px-bx-0.5f, fy = py-by-0.5f, fz = pz-bz-0.5f;
                float wx = (oi==0) ? 0.5f*(0.5f-fx)*(0.5f-fx) : (oi==1) ? 0.75f-fx*fx : 0.5f*(0.5f+fx)*(0.5f+fx);
                float wy = (oj==0) ? 0.5f*(0.5f-fy)*(0.5f-fy) : (oj==1) ? 0.75f-fy*fy : 0.5f*(0.5f+fy)*(0.5f+fy);
                wxy[p] = wx*wy;
                wz[p][0]=0.5f*(0.5f-fz)*(0.5f-fz); wz[p][1]=0.75f-fz*fz; wz[p][2]=0.5f*(0.5f+fz)*(0.5f+fz);
                cb[p]   = (bx+oi)*GHW + (by+oj)*GD + bz;
                bsel[p] = (gp >= N) ? 1 : 0;
            }
            float y[3][2];
            #pragma unroll
            for (int ok = 0; ok < 3; ++ok) { y[ok][0] = bco; y[ok][1] = bco; }
            #pragma unroll
            for (int ci = 0; ci < 32; ++ci) {
                float x0 = xr[0][ci], x1 = xr[1][ci];
                #pragma unroll
                for (int ok = 0; ok < 3; ++ok) {
                    float kv = kreg[ok][ci];
                    y[ok][0] += x0*kv; y[ok][1] += x1*kv;
                }
            }
            #pragma unroll
            for (int ok = 0; ok < 3; ++ok) {
                atomAdd(dst + ((size_t)(bsel[0]*32 + co))*GDHW + (size_t)(cb[0]+ok), wxy[0]*wz[0][ok]*y[ok][0]);
                atomAdd(dst + ((size_t)(bsel[1]*32 + co))*GDHW + (size_t)(cb[1]+ok), wxy[1]*wz[1][ok]*y[ok][1]);
            }
        }
    }
}

extern "C" void kernel_launch(void* const* d_in, const int* in_sizes, int n_in,
                              void* d_out, int out_size, void* d_ws, size_t ws_size,
                              hipStream_t stream) {
    const float* x    = (const float*)d_in[0];
    const float* pos  = (const float*)d_in[1];
    const float* kern = (const float*)d_in[2];
    const float* bias = (const float*)d_in[3];
    float* out = (float*)d_out;

    const int N     = in_sizes[0] / (2*CI);   // per-batch particle count
    const int total = 2*N;

    // workspace layout (bytes)
    const size_t offX    = 0;                                   // X: total*32 f32
    const size_t offW    = offX + (size_t)total*32*4;           // W: total*9 f32
    const size_t offCnt  = offW + (size_t)total*9*4;            // counts: NBINS u32
    const size_t offOffs = offCnt + (size_t)NBINS*4;            // offs: NBINS+1 u32
    const size_t offBin  = (offOffs + (size_t)(NBINS+1)*4 + 255) & ~(size_t)255;
    const size_t offRank = offBin + (size_t)total*4;
    const size_t offBsum = offRank + (size_t)total*4;
    const size_t wsNeed  = offBsum + (size_t)NSCAN_BLOCKS*4;

    if (ws_size >= wsNeed) {
        char* wsb = (char*)d_ws;
        float*    X      = (float*)   (wsb + offX);
        float*    W      = (float*)   (wsb + offW);
        unsigned* counts = (unsigned*)(wsb + offCnt);
        unsigned* offs   = (unsigned*)(wsb + offOffs);
        unsigned* binA   = (unsigned*)(wsb + offBin);
        unsigned* rankA  = (unsigned*)(wsb + offRank);
        unsigned* bsum   = (unsigned*)(wsb + offBsum);

        (void)hipMemsetAsync(counts, 0, (size_t)NBINS*4, stream);
        const int pb = (total + 255)/256;
        hist_kernel   <<<dim3(pb),           dim3(256), 0, stream>>>(pos, counts, binA, rankA, N, total);
        scan1_kernel  <<<dim3(NSCAN_BLOCKS), dim3(256), 0, stream>>>(counts, offs, bsum);
        scan2_kernel  <<<dim3(1),            dim3(256), 0, stream>>>(bsum);
        scan3_kernel  <<<dim3(NSCAN_BLOCKS), dim3(256), 0, stream>>>(offs, bsum, total);
        reorder_kernel<<<dim3(pb),           dim3(256), 0, stream>>>(x, pos, offs, binA, rankA, X, W, total);
        gather_kernel <<<dim3(2*66*66),      dim3(256), 0, stream>>>(X, W, offs, kern, bias, out);
    } else {
        (void)hipMemsetAsync(out, 0, (size_t)out_size * sizeof(float), stream);
        const int nPairs = (total + 1) / 2;
        p2g_fallback<<<dim3(2048), dim3(256), 0, stream>>>(x, pos, kern, bias, out, N, nPairs);
    }
}

// Round 4
// 1998.972 us; speedup vs baseline: 1.6120x; 1.6120x over previous
//
#include <hip/hip_runtime.h>

// Grid constants (padded 66^3)
#define GD   66
#define GHW  (66*66)
#define GDHW (66*66*66)
#define CI   32
#define CO   32
#define NBINS (2*64*64*64)      // batch * 64^3 = 524288 bins
#define NSCAN_BLOCKS 2048       // NBINS / 256

__device__ __forceinline__ void atomAdd(float* p, float v) {
    unsafeAtomicAdd(p, v);      // native global_atomic_add_f32 on gfx950
}

// ---------------- sort-gather path ----------------
// r0/r1: scatter hits the L2 atomic-op wall (345.6M ops ~ 1 op/channel/cycle
// -> 1117us floor). r3: naive gather was latency-bound (~1800 cyc/visit:
// dependent global offs loads + intra-wave divergence). This version: LDS
// bin ranges, full-wave cells with parity-split particles, x loaded once per
// (particle,t) feeding 3 register-K dots.

// K1: histogram + per-particle (bin, rank)
__global__ __launch_bounds__(256) void hist_kernel(
    const float* __restrict__ pos, unsigned* __restrict__ counts,
    unsigned* __restrict__ binA, unsigned* __restrict__ rankA,
    int N, int total)
{
    int gp = blockIdx.x*256 + threadIdx.x;
    if (gp >= total) return;
    float px = pos[gp*3+0]*64.f, py = pos[gp*3+1]*64.f, pz = pos[gp*3+2]*64.f;
    int bx = (int)px, by = (int)py, bz = (int)pz;     // base in [0,63]
    int b  = (gp >= N) ? 1 : 0;
    unsigned bin = (((unsigned)(b*64 + bx))*64u + (unsigned)by)*64u + (unsigned)bz;
    unsigned r = atomicAdd(&counts[bin], 1u);
    binA[gp] = bin; rankA[gp] = r;
}

// S1: per-block (256 bins) local exclusive scan + block sums
__global__ __launch_bounds__(256) void scan1_kernel(
    const unsigned* __restrict__ counts, unsigned* __restrict__ offs,
    unsigned* __restrict__ bsum)
{
    __shared__ unsigned ws[4];
    int i = blockIdx.x*256 + threadIdx.x;
    int lane = threadIdx.x & 63, wid = threadIdx.x >> 6;
    unsigned v = counts[i], s = v;
    #pragma unroll
    for (int d = 1; d < 64; d <<= 1) { unsigned n = __shfl_up(s, d, 64); if (lane >= d) s += n; }
    if (lane == 63) ws[wid] = s;
    __syncthreads();
    if (threadIdx.x == 0) {
        unsigned r = 0;
        for (int w = 0; w < 4; ++w) { unsigned t = ws[w]; ws[w] = r; r += t; }
        bsum[blockIdx.x] = r;
    }
    __syncthreads();
    offs[i] = ws[wid] + s - v;
}

// S2: single block scans the 2048 block sums (exclusive, in place)
__global__ __launch_bounds__(256) void scan2_kernel(unsigned* __restrict__ bsum)
{
    __shared__ unsigned ws[4];
    __shared__ unsigned runsh;
    if (threadIdx.x == 0) runsh = 0;
    __syncthreads();
    int lane = threadIdx.x & 63, wid = threadIdx.x >> 6;
    for (int c = 0; c < NSCAN_BLOCKS; c += 256) {
        unsigned v = bsum[c + threadIdx.x], s = v;
        #pragma unroll
        for (int d = 1; d < 64; d <<= 1) { unsigned n = __shfl_up(s, d, 64); if (lane >= d) s += n; }
        if (lane == 63) ws[wid] = s;
        __syncthreads();
        unsigned run = runsh;
        __syncthreads();                    // all reads of runsh/ws done
        if (threadIdx.x == 0) {
            unsigned r = 0;
            for (int w = 0; w < 4; ++w) { unsigned t = ws[w]; ws[w] = r; r += t; }
            runsh = run + r;
        }
        __syncthreads();                    // ws prefixes + runsh ready
        bsum[c + threadIdx.x] = run + ws[wid] + s - v;
        __syncthreads();                    // protect ws for next chunk
    }
}

// S3: add block prefix; set offs[NBINS] = total
__global__ __launch_bounds__(256) void scan3_kernel(
    unsigned* __restrict__ offs, const unsigned* __restrict__ bsum, int total)
{
    int i = blockIdx.x*256 + threadIdx.x;
    offs[i] += bsum[blockIdx.x];
    if (i == 0) offs[NBINS] = (unsigned)total;
}

// K3: reorder particles into bin-sorted SoA: X[p][32], W[p][9] (spline weights)
__global__ __launch_bounds__(256) void reorder_kernel(
    const float* __restrict__ x, const float* __restrict__ pos,
    const unsigned* __restrict__ offs, const unsigned* __restrict__ binA,
    const unsigned* __restrict__ rankA,
    float* __restrict__ X, float* __restrict__ W, int total)
{
    int gp = blockIdx.x*256 + threadIdx.x;
    if (gp >= total) return;
    unsigned dst = offs[binA[gp]] + rankA[gp];
    const float4* xs = (const float4*)(x + (size_t)gp*32);
    float4* xd = (float4*)(X + (size_t)dst*32);
    #pragma unroll
    for (int i = 0; i < 8; ++i) xd[i] = xs[i];
    float px = pos[gp*3+0]*64.f, py = pos[gp*3+1]*64.f, pz = pos[gp*3+2]*64.f;
    int bx = (int)px, by = (int)py, bz = (int)pz;
    float fx = px-bx-0.5f, fy = py-by-0.5f, fz = pz-bz-0.5f;
    float* w = W + (size_t)dst*9;
    w[0]=0.5f*(0.5f-fx)*(0.5f-fx); w[1]=0.75f-fx*fx; w[2]=0.5f*(0.5f+fx)*(0.5f+fx);
    w[3]=0.5f*(0.5f-fy)*(0.5f-fy); w[4]=0.75f-fy*fy; w[5]=0.5f*(0.5f+fy)*(0.5f+fy);
    w[6]=0.5f*(0.5f-fz)*(0.5f-fz); w[7]=0.75f-fz*fz; w[8]=0.5f*(0.5f+fz)*(0.5f+fz);
}

// K4 v2: gather. Block = (b, cx, cy, z-chunk of 32 cells); 4 waves; wave owns
// 8 CONSECUTIVE cells. Bin ranges in LDS. Lanes: co = lane&31, parity = lane>>5
// (even/odd particles of the same bin -> near-zero divergence). Per (particle,t):
// x loaded once (8x float4 broadcast), 3 dots vs register kreg[3][32], static
// accumulation into acc[j-2+ok] (j unrolled -> no scratch).
__global__ __launch_bounds__(256) void gather_kernel(
    const float* __restrict__ X, const float* __restrict__ W,
    const unsigned* __restrict__ offs, const float* __restrict__ kern,
    const float* __restrict__ bias, float* __restrict__ out)
{
    __shared__ unsigned offs_l[9*65];
    __shared__ float tile[32][33];

    int bid = blockIdx.x;
    const int chunk = bid % 3; bid /= 3;
    const int cy = bid % 66;   bid /= 66;
    const int cx = bid % 66;
    const int b  = bid / 66;

    const int lane = threadIdx.x & 63;
    const int co   = lane & 31;
    const int par  = lane >> 5;            // particle parity
    const int w    = threadIdx.x >> 6;     // wave id 0..3
    const float bco = bias[co];

    // stage bin ranges for the 9 (gx,gy)=(cx-oi,cy-oj) columns (65 offs each)
    for (int e2 = threadIdx.x; e2 < 9*65; e2 += 256) {
        const int tcol = e2 / 65, gz = e2 % 65;
        const int gx = cx - tcol/3, gy = cy - tcol%3;
        unsigned v = 0;
        if ((unsigned)gx < 64u && (unsigned)gy < 64u)
            v = offs[(((unsigned)(b*64+gx))*64u + (unsigned)gy)*64u + (unsigned)gz];
        offs_l[e2] = v;
    }
    __syncthreads();

    const int c0 = chunk*32 + w*8;         // first owned cell
    float acc[8];
    #pragma unroll
    for (int a = 0; a < 8; ++a) acc[a] = 0.f;

    for (int t = 0; t < 9; ++t) {          // t = oi*3 + oj
        const int oi = t/3, oj = t%3;
        if ((unsigned)(cx-oi) >= 64u || (unsigned)(cy-oj) >= 64u) continue;

        float kreg[3][32];                  // K[oi][oj][ok][ci][co]
        #pragma unroll
        for (int ok = 0; ok < 3; ++ok) {
            const float* kp = kern + (size_t)(t*3 + ok)*1024 + co;
            #pragma unroll
            for (int ci = 0; ci < 32; ++ci) kreg[ok][ci] = kp[ci*32];
        }

        #pragma unroll
        for (int j = 0; j < 10; ++j) {      // bin slot: gz = c0-2+j
            const int gz = c0 - 2 + j;
            if (gz < 0 || gz > 63) continue;                 // wave-uniform
            const unsigned s = offs_l[t*65 + gz];
            const unsigned e = offs_l[t*65 + gz + 1];
            for (unsigned p = s + (unsigned)par; p < e; p += 2) {
                const float4* xp = (const float4*)(X + (size_t)p*32);
                const float*  wp = W + (size_t)p*9;
                const float wxy = wp[oi]*wp[3+oj];
                float d0 = bco, d1 = bco, d2 = bco;
                #pragma unroll
                for (int i = 0; i < 8; ++i) {
                    float4 v = xp[i];
                    d0 += v.x*kreg[0][4*i+0]; d1 += v.x*kreg[1][4*i+0]; d2 += v.x*kreg[2][4*i+0];
                    d0 += v.y*kreg[0][4*i+1]; d1 += v.y*kreg[1][4*i+1]; d2 += v.y*kreg[2][4*i+1];
                    d0 += v.z*kreg[0][4*i+2]; d1 += v.z*kreg[1][4*i+2]; d2 += v.z*kreg[2][4*i+2];
                    d0 += v.w*kreg[0][4*i+3]; d1 += v.w*kreg[1][4*i+3]; d2 += v.w*kreg[2][4*i+3];
                }
                // cell = gz+ok -> acc slot a = j-2+ok (compile-time per j,ok)
                if (j >= 2)           acc[j-2] += wxy*wp[6]*d0;
                if (j >= 1 && j <= 8) acc[j-1] += wxy*wp[7]*d1;
                if (j <= 7)           acc[j]   += wxy*wp[8]*d2;
            }
        }
    }

    // combine parity halves (lane ^ 32 holds the other parity's partial)
    #pragma unroll
    for (int a = 0; a < 8; ++a) acc[a] += __shfl_xor(acc[a], 32, 64);

    if (par == 0) {
        #pragma unroll
        for (int a = 0; a < 8; ++a) {
            const int cl = w*8 + a;
            if (chunk*32 + cl < GD) tile[cl][co] = acc[a];
        }
    }
    __syncthreads();
    // coalesced write-out: consecutive threads -> consecutive cz
    for (int idx = threadIdx.x; idx < 32*32; idx += 256) {
        const int co2 = idx >> 5, cl = idx & 31;
        const int cz = chunk*32 + cl;
        if (cz < GD)
            out[((size_t)(b*32 + co2))*GDHW + (size_t)(cx*GHW + cy*GD + cz)] = tile[cl][co2];
    }
}

// ---------------- fallback: direct atomic scatter ----------------
__global__ __launch_bounds__(256) void p2g_fallback(
    const float* __restrict__ x, const float* __restrict__ pos,
    const float* __restrict__ kern, const float* __restrict__ bias,
    float* __restrict__ dst, int N, int nPairs)
{
    const int co   = threadIdx.x & 31;
    const int half = threadIdx.x >> 5;
    const float bco = bias[co];
    const int halvesTotal = gridDim.x * 8;

    for (int t = 0; t < 9; ++t) {
        const int oi = t / 3, oj = t - 3*oi;
        float kreg[3][32];
        #pragma unroll
        for (int ok = 0; ok < 3; ++ok) {
            const float* kp = kern + (size_t)(t*3 + ok)*1024 + co;
            #pragma unroll
            for (int ci = 0; ci < 32; ++ci) kreg[ok][ci] = kp[ci*32];
        }
        for (int pp = blockIdx.x*8 + half; pp < nPairs; pp += halvesTotal) {
            const int g0 = pp*2;
            float xr[2][32];
            #pragma unroll
            for (int p = 0; p < 2; ++p) {
                const float4* xp = (const float4*)(x + (size_t)(g0+p)*CI);
                #pragma unroll
                for (int i = 0; i < 8; ++i) {
                    float4 v = xp[i];
                    xr[p][4*i+0]=v.x; xr[p][4*i+1]=v.y; xr[p][4*i+2]=v.z; xr[p][4*i+3]=v.w;
                }
            }
            float wxy[2], wz[2][3]; int cb[2], bsel[2];
            #pragma unroll
            for (int p = 0; p < 2; ++p) {
                const int gp = g0 + p;
                float px = pos[gp*3+0]*64.f, py = pos[gp*3+1]*64.f, pz = pos[gp*3+2]*64.f;
                int bx = (int)px, by = (int)py, bz = (int)pz;
                float fx = px-bx-0.5f, fy = py-by-0.5f, fz = pz-bz-0.5f;
                float wx = (oi==0) ? 0.5f*(0.5f-fx)*(0.5f-fx) : (oi==1) ? 0.75f-fx*fx : 0.5f*(0.5f+fx)*(0.5f+fx);
                float wy = (oj==0) ? 0.5f*(0.5f-fy)*(0.5f-fy) : (oj==1) ? 0.75f-fy*fy : 0.5f*(0.5f+fy)*(0.5f+fy);
                wxy[p] = wx*wy;
                wz[p][0]=0.5f*(0.5f-fz)*(0.5f-fz); wz[p][1]=0.75f-fz*fz; wz[p][2]=0.5f*(0.5f+fz)*(0.5f+fz);
                cb[p]   = (bx+oi)*GHW + (by+oj)*GD + bz;
                bsel[p] = (gp >= N) ? 1 : 0;
            }
            float y[3][2];
            #pragma unroll
            for (int ok = 0; ok < 3; ++ok) { y[ok][0] = bco; y[ok][1] = bco; }
            #pragma unroll
            for (int ci = 0; ci < 32; ++ci) {
                float x0 = xr[0][ci], x1 = xr[1][ci];
                #pragma unroll
                for (int ok = 0; ok < 3; ++ok) {
                    float kv = kreg[ok][ci];
                    y[ok][0] += x0*kv; y[ok][1] += x1*kv;
                }
            }
            #pragma unroll
            for (int ok = 0; ok < 3; ++ok) {
                atomAdd(dst + ((size_t)(bsel[0]*32 + co))*GDHW + (size_t)(cb[0]+ok), wxy[0]*wz[0][ok]*y[ok][0]);
                atomAdd(dst + ((size_t)(bsel[1]*32 + co))*GDHW + (size_t)(cb[1]+ok), wxy[1]*wz[1][ok]*y[ok][1]);
            }
        }
    }
}

extern "C" void kernel_launch(void* const* d_in, const int* in_sizes, int n_in,
                              void* d_out, int out_size, void* d_ws, size_t ws_size,
                              hipStream_t stream) {
    const float* x    = (const float*)d_in[0];
    const float* pos  = (const float*)d_in[1];
    const float* kern = (const float*)d_in[2];
    const float* bias = (const float*)d_in[3];
    float* out = (float*)d_out;

    const int N     = in_sizes[0] / (2*CI);   // per-batch particle count
    const int total = 2*N;

    // workspace layout (bytes)
    const size_t offX    = 0;                                   // X: total*32 f32
    const size_t offW    = offX + (size_t)total*32*4;           // W: total*9 f32
    const size_t offCnt  = offW + (size_t)total*9*4;            // counts: NBINS u32
    const size_t offOffs = offCnt + (size_t)NBINS*4;            // offs: NBINS+1 u32
    const size_t offBin  = (offOffs + (size_t)(NBINS+1)*4 + 255) & ~(size_t)255;
    const size_t offRank = offBin + (size_t)total*4;
    const size_t offBsum = offRank + (size_t)total*4;
    const size_t wsNeed  = offBsum + (size_t)NSCAN_BLOCKS*4;

    if (ws_size >= wsNeed) {
        char* wsb = (char*)d_ws;
        float*    X      = (float*)   (wsb + offX);
        float*    W      = (float*)   (wsb + offW);
        unsigned* counts = (unsigned*)(wsb + offCnt);
        unsigned* offs   = (unsigned*)(wsb + offOffs);
        unsigned* binA   = (unsigned*)(wsb + offBin);
        unsigned* rankA  = (unsigned*)(wsb + offRank);
        unsigned* bsum   = (unsigned*)(wsb + offBsum);

        (void)hipMemsetAsync(counts, 0, (size_t)NBINS*4, stream);
        const int pb = (total + 255)/256;
        hist_kernel   <<<dim3(pb),           dim3(256), 0, stream>>>(pos, counts, binA, rankA, N, total);
        scan1_kernel  <<<dim3(NSCAN_BLOCKS), dim3(256), 0, stream>>>(counts, offs, bsum);
        scan2_kernel  <<<dim3(1),            dim3(256), 0, stream>>>(bsum);
        scan3_kernel  <<<dim3(NSCAN_BLOCKS), dim3(256), 0, stream>>>(offs, bsum, total);
        reorder_kernel<<<dim3(pb),           dim3(256), 0, stream>>>(x, pos, offs, binA, rankA, X, W, total);
        gather_kernel <<<dim3(2*66*66*3),    dim3(256), 0, stream>>>(X, W, offs, kern, bias, out);
    } else {
        (void)hipMemsetAsync(out, 0, (size_t)out_size * sizeof(float), stream);
        const int nPairs = (total + 1) / 2;
        p2g_fallback<<<dim3(2048), dim3(256), 0, stream>>>(x, pos, kern, bias, out, N, nPairs);
    }
}